// Round 3
// baseline (156.540 us; speedup 1.0000x reference)
//
#include <hip/hip_runtime.h>
#include <hip/hip_bf16.h>
#include <math.h>

// Bilateral Gaussian filter: out[b,c,i] = sum_j exp(-0.5|f_i-f_j|^2) * cur[b,c,j]
// f = [y/8, x/8, r/.5, g/.5, b/.5] (D=5). B=2, C=21, N=9216.
//
// w_ij = exp2( (log2e*fi)·fj + ei' + ej' ) computed on VALU (pk_fma dot,
// native v_exp), packed to bf16 via integer-round + v_perm directly into the
// MFMA A-fragment (lane l owns W[m=l&31][k=(l>>5)*8+t]); V staged in LDS in
// B-fragment layout (conflict-free dword-linear staging);
// v_mfma_f32_32x32x16_bf16 accumulates 32i x 32c in fp32.

#define HH 96
#define WW 96
#define NN (HH * WW)   // 9216
#define NB 2
#define NC 21

typedef __attribute__((ext_vector_type(8))) short short8;
typedef __attribute__((ext_vector_type(16))) float f32x16;
typedef __attribute__((ext_vector_type(2))) float float2v;

constexpr float INV_TA = 0.125f;  // 1/theta_alpha
constexpr float INV_TB = 2.0f;    // 1/theta_beta
constexpr float LOG2E  = 1.44269504088896340736f;

constexpr int BLK  = 256;          // 4 waves
constexpr int ITILE = 64;          // i per block (2 subtiles of 32)
constexpr int NIT  = NN / ITILE;   // 144
constexpr int G    = 9;            // j-groups
constexpr int JG   = NN / G;       // 1024 j per group
constexpr int JS   = 256;          // j per staged piece
constexpr int NP   = JG / JS;      // 4 pieces
constexpr int NCHUNK = JS / 16;    // 16 chunks of 16 j
constexpr int JBLK = JS / 8;       // 32

// LDS: V bf16 [jblk=32][c=32][jj=8] (16 KB) + features fp32 [6][264] (6.3 KB)
constexpr int FS  = JS + 8;                 // 264 floats/row (16B-aligned rows)
constexpr int VDW = JBLK * 32 * 4;          // 4096 dwords of packed bf16 pairs
constexpr int SMEM_BYTES = VDW * 4 + 6 * FS * 4;  // 22752 B

__global__ __launch_bounds__(BLK)
void perm_gauss_mfma(const float* __restrict__ cur,   // [B, NC, N]
                     const float* __restrict__ img,   // [B, 3, N]
                     float* __restrict__ out) {       // [B, NC, N]
    __shared__ __align__(16) char smem[SMEM_BYTES];
    unsigned* vlds = (unsigned*)smem;                    // packed bf16 pairs
    float* flds = (float*)(smem + VDW * 4);              // features
    float* tile = (float*)smem;                          // epilogue alias

    const int tid   = threadIdx.x;
    const int lane  = tid & 63;
    const int wave  = tid >> 6;
    const int isub  = wave & 1;   // which 32-i subtile
    const int jpart = wave >> 1;  // which half of the chunks
    const int il    = lane & 31;  // A-frag m (i) / C-frag col (c)
    const int half  = lane >> 5;  // k-half selector

    const int it = blockIdx.x;    // i-tile
    const int g  = blockIdx.y;    // j-group
    const int b  = blockIdx.z;    // batch

    const int ibase = it * ITILE;
    const float* curb = cur + (size_t)b * NC * NN;
    const float* imgb = img + (size_t)b * 3 * NN;
    float* outb = out + (size_t)b * NC * NN;

    // ---- per-lane i features, pre-scaled by log2(e) ----
    const int ig = ibase + isub * 32 + il;
    const float fi0 = (float)(ig / WW) * INV_TA;
    const float fi1 = (float)(ig % WW) * INV_TA;
    const float fi2 = imgb[ig] * INV_TB;
    const float fi3 = imgb[NN + ig] * INV_TB;
    const float fi4 = imgb[2 * NN + ig] * INV_TB;
    const float eis = -0.5f * LOG2E * (fi0 * fi0 + fi1 * fi1 + fi2 * fi2 +
                                       fi3 * fi3 + fi4 * fi4);
    const float2v s0 = {fi0 * LOG2E, fi0 * LOG2E};
    const float2v s1 = {fi1 * LOG2E, fi1 * LOG2E};
    const float2v s2 = {fi2 * LOG2E, fi2 * LOG2E};
    const float2v s3 = {fi3 * LOG2E, fi3 * LOG2E};
    const float2v s4 = {fi4 * LOG2E, fi4 * LOG2E};
    const float2v eiv = {eis, eis};

    f32x16 acc;
    #pragma unroll
    for (int r = 0; r < 16; ++r) acc[r] = 0.0f;

    const int jg0 = g * JG;
    for (int p = 0; p < NP; ++p) {
        __syncthreads();  // previous piece fully consumed
        const int jp0 = jg0 + p * JS;

        // ---- stage features: one j per thread (JS == BLK) ----
        {
            const int j = jp0 + tid;
            const float y = (float)(j / WW);
            const float x = (float)(j % WW);
            const float f0 = y * INV_TA;
            const float f1 = x * INV_TA;
            const float f2 = imgb[j] * INV_TB;
            const float f3 = imgb[NN + j] * INV_TB;
            const float f4 = imgb[2 * NN + j] * INV_TB;
            flds[0 * FS + tid] = f0;
            flds[1 * FS + tid] = f1;
            flds[2 * FS + tid] = f2;
            flds[3 * FS + tid] = f3;
            flds[4 * FS + tid] = f4;
            flds[5 * FS + tid] = -0.5f * LOG2E *
                (f0 * f0 + f1 * f1 + f2 * f2 + f3 * f3 + f4 * f4);
        }
        // ---- stage V, dword-linear (conflict-free, coalesced-ish) ----
        for (int d = tid; d < VDW; d += BLK) {  // 16 iters
            const int jblk = d >> 7;        // /128
            const int rem  = d & 127;
            const int c    = rem >> 2;
            const int jjp  = rem & 3;
            float v0 = 0.0f, v1 = 0.0f;
            if (c < NC) {
                const float2v v = *(const float2v*)
                    &curb[(size_t)c * NN + jp0 + jblk * 8 + jjp * 2];
                v0 = v.x; v1 = v.y;
            }
            const unsigned u0 = __float_as_uint(v0) + 0x8000u;
            const unsigned u1 = __float_as_uint(v1) + 0x8000u;
            vlds[d] = __builtin_amdgcn_perm(u1, u0, 0x07060302u);
        }
        __syncthreads();

        // ---- main loop: this wave's 8 chunks of 16 j ----
        for (int q = 0; q < NCHUNK / 2; ++q) {
            const int chunk = jpart + 2 * q;
            const int jb = chunk * 16;
            const float* fp = &flds[jb + half * 8];

            union { float4 q4[2]; float2v p[4]; } f[6];
            #pragma unroll
            for (int d = 0; d < 6; ++d) {
                f[d].q4[0] = *(const float4*)(fp + d * FS);
                f[d].q4[1] = *(const float4*)(fp + d * FS + 4);
            }
            const short8 bfrag = ((const short8*)vlds)
                [(size_t)(chunk * 2 + half) * 32 + il];

            union { unsigned dw[4]; short8 v; } af;
            #pragma unroll
            for (int t = 0; t < 4; ++t) {
                float2v arg = eiv + f[5].p[t];
                arg += s0 * f[0].p[t];
                arg += s1 * f[1].p[t];
                arg += s2 * f[2].p[t];
                arg += s3 * f[3].p[t];
                arg += s4 * f[4].p[t];
                const float w0 = exp2f(arg.x);
                const float w1 = exp2f(arg.y);
                const unsigned u0 = __float_as_uint(w0) + 0x8000u;
                const unsigned u1 = __float_as_uint(w1) + 0x8000u;
                af.dw[t] = __builtin_amdgcn_perm(u1, u0, 0x07060302u);
            }
            acc = __builtin_amdgcn_mfma_f32_32x32x16_bf16(af.v, bfrag, acc, 0, 0, 0);
        }
    }

    // ---- epilogue: per-wave LDS transpose, then coalesced atomics ----
    __syncthreads();  // all waves done reading staged LDS (tile aliases it)
    float* mytile = tile + wave * 32 * 33;
    // D layout: col(c) = lane&31, row(i) = (r&3) + 8*(r>>2) + 4*half
    #pragma unroll
    for (int r = 0; r < 16; ++r) {
        const int row = (r & 3) + 8 * (r >> 2) + 4 * half;
        mytile[row * 33 + il] = acc[r];
    }
    #pragma unroll
    for (int cc = 0; cc < 11; ++cc) {
        const int c = 2 * cc + half;
        if (c < NC) {
            const float v = mytile[il * 33 + c];
            atomicAdd(&outb[(size_t)c * NN + ibase + isub * 32 + il], v);
        }
    }
}

extern "C" void kernel_launch(void* const* d_in, const int* in_sizes, int n_in,
                              void* d_out, int out_size, void* d_ws, size_t ws_size,
                              hipStream_t stream) {
    const float* cur = (const float*)d_in[0];  // cur_state  [2,21,96,96]
    const float* img = (const float*)d_in[1];  // input_image [2,3,96,96]
    float* out = (float*)d_out;

    // d_out is poisoned with 0xAA before every timed launch -> zero it.
    hipMemsetAsync(out, 0, (size_t)NB * NC * NN * sizeof(float), stream);

    dim3 grid(NIT, G, NB);  // 144 x 9 x 2 = 2592 blocks
    perm_gauss_mfma<<<grid, BLK, 0, stream>>>(cur, img, out);
}

// Round 4
// 143.957 us; speedup vs baseline: 1.0874x; 1.0874x over previous
//
#include <hip/hip_runtime.h>
#include <hip/hip_bf16.h>
#include <math.h>

// Bilateral Gaussian filter: out[b,c,i] = sum_j exp(-0.5|f_i-f_j|^2) * cur[b,c,j]
// f = [y/8, x/8, r/.5, g/.5, b/.5] (D=5). B=2, C=21, N=9216.
//
// Flash-style: VALU computes w_ij = exp2(si·fj + ei' + ej') directly in the
// MFMA A-fragment layout (lane l owns W[m=l&31][k=(l>>5)*8+t]); V staged in
// LDS in (bank-swizzled) B-fragment layout; v_mfma_f32_32x32x16_bf16
// accumulates 32i x 32c in fp32. Latency-focused round: JS=256 pieces for
// ~5-7 blocks/CU occupancy, staging that is simultaneously coalesced
// (global) and conflict-free (LDS) via low-3-bit XOR swizzle of c by jblk.

#define HH 96
#define WW 96
#define NN (HH * WW)   // 9216
#define NB 2
#define NC 21

typedef __attribute__((ext_vector_type(8))) short short8;
typedef __attribute__((ext_vector_type(16))) float f32x16;
typedef __attribute__((ext_vector_type(2))) float float2v;

constexpr float INV_TA = 0.125f;  // 1/theta_alpha
constexpr float INV_TB = 2.0f;    // 1/theta_beta
constexpr float LOG2E  = 1.44269504088896340736f;

constexpr int BLK   = 256;         // 4 waves
constexpr int ITILE = 64;          // i per block (2 subtiles of 32)
constexpr int NIT   = NN / ITILE;  // 144
constexpr int G     = 12;          // j-groups
constexpr int JG    = NN / G;      // 768 j per group
constexpr int JS    = 256;         // j per staged piece
constexpr int NP    = JG / JS;     // 3 pieces
constexpr int NCHUNK = JS / 16;    // 16 chunks of 16 j
constexpr int NJBLK  = JS / 8;     // 32 j-blocks

// LDS: V bf16 swizzled [jblk=32][c^]{32}[jj=8] (16 KB)
//      + features fp32 [6][264] (6.3 KB)  = 22720 B total
constexpr int FS  = JS + 8;                 // 264 floats per feature plane
constexpr int VDW = NJBLK * 32 * 4;         // 4096 dwords of packed bf16 pairs
constexpr int SMEM_BYTES = VDW * 4 + 6 * FS * 4;

#if defined(__has_builtin)
#if __has_builtin(__builtin_amdgcn_exp2f)
#define EXP2F(x) __builtin_amdgcn_exp2f(x)
#endif
#endif
#ifndef EXP2F
#define EXP2F(x) exp2f(x)
#endif

__global__ __launch_bounds__(BLK)
void perm_gauss_mfma(const float* __restrict__ cur,   // [B, NC, N]
                     const float* __restrict__ img,   // [B, 3, N]
                     float* __restrict__ out) {       // [B, NC, N]
    __shared__ __align__(16) char smem[SMEM_BYTES];
    unsigned* vlds = (unsigned*)smem;           // packed bf16 pairs (swizzled)
    float* flds = (float*)(smem + VDW * 4);     // feature planes
    float* tile = (float*)smem;                 // epilogue alias

    const int tid   = threadIdx.x;
    const int lane  = tid & 63;
    const int wave  = tid >> 6;
    const int isub  = wave & 1;   // which 32-i subtile
    const int jpart = wave >> 1;  // which half of the chunks
    const int il    = lane & 31;  // A-frag m (i) / D col (c)
    const int half  = lane >> 5;  // k-half selector

    const int it = blockIdx.x;    // i-tile
    const int g  = blockIdx.y;    // j-group
    const int b  = blockIdx.z;    // batch

    const int ibase = it * ITILE;
    const float* curb = cur + (size_t)b * NC * NN;
    const float* imgb = img + (size_t)b * 3 * NN;
    float* outb = out + (size_t)b * NC * NN;

    // ---- per-lane i features, pre-scaled by log2(e) ----
    const int ig = ibase + isub * 32 + il;
    const float fi0 = (float)(ig / WW) * INV_TA;
    const float fi1 = (float)(ig % WW) * INV_TA;
    const float fi2 = imgb[ig] * INV_TB;
    const float fi3 = imgb[NN + ig] * INV_TB;
    const float fi4 = imgb[2 * NN + ig] * INV_TB;
    const float eis = -0.5f * LOG2E * (fi0 * fi0 + fi1 * fi1 + fi2 * fi2 +
                                       fi3 * fi3 + fi4 * fi4);
    const float si0 = fi0 * LOG2E;
    const float si1 = fi1 * LOG2E;
    const float si2 = fi2 * LOG2E;
    const float si3 = fi3 * LOG2E;
    const float si4 = fi4 * LOG2E;

    f32x16 acc;
    #pragma unroll
    for (int r = 0; r < 16; ++r) acc[r] = 0.0f;

    const int jg0 = g * JG;
    for (int p = 0; p < NP; ++p) {
        __syncthreads();  // previous piece fully consumed
        const int jp0 = jg0 + p * JS;

        // ---- stage features: one j per thread (JS == BLK) ----
        {
            const int j = jp0 + tid;
            const float y = (float)(j / WW);
            const float x = (float)(j % WW);
            const float f0 = y * INV_TA;
            const float f1 = x * INV_TA;
            const float f2 = imgb[j] * INV_TB;
            const float f3 = imgb[NN + j] * INV_TB;
            const float f4 = imgb[2 * NN + j] * INV_TB;
            flds[0 * FS + tid] = f0;
            flds[1 * FS + tid] = f1;
            flds[2 * FS + tid] = f2;
            flds[3 * FS + tid] = f3;
            flds[4 * FS + tid] = f4;
            flds[5 * FS + tid] = -0.5f * LOG2E *
                (f0 * f0 + f1 * f1 + f2 * f2 + f3 * f3 + f4 * f4);
        }

        // ---- stage V: coalesced reads, swizzled conflict-free writes ----
        // dword task d: c = d>>7 (channel), pp = d&127 (j-pair).
        // Consecutive lanes -> consecutive pairs of one channel row (coalesced).
        // LDS 16B block (jblk, c) lives at jblk*32 + (c ^ (jblk & 7)).
        #pragma unroll
        for (int itv = 0; itv < VDW / BLK; ++itv) {   // 16 iterations
            const int d  = itv * BLK + tid;
            const int c  = d >> 7;
            const int pp = d & 127;
            const int jblk = pp >> 2;
            const int ps   = pp & 3;
            float v0 = 0.0f, v1 = 0.0f;
            if (c < NC) {
                const float2v v = *(const float2v*)
                    &curb[(size_t)c * NN + jp0 + 2 * pp];
                v0 = v.x; v1 = v.y;
            }
            const unsigned u0 = __float_as_uint(v0) + 0x8000u;
            const unsigned u1 = __float_as_uint(v1) + 0x8000u;
            vlds[(jblk * 32 + (c ^ (jblk & 7))) * 4 + ps] =
                __builtin_amdgcn_perm(u1, u0, 0x07060302u);
        }
        __syncthreads();

        // ---- main loop: this wave's 8 chunks of 16 j ----
        for (int q = 0; q < NCHUNK / 2; ++q) {
            const int chunk = jpart + 2 * q;
            const int jb = chunk * 16;
            const float* fp = &flds[jb + half * 8];

            float f[6][8];
            #pragma unroll
            for (int d = 0; d < 6; ++d) {
                *(float4*)&f[d][0] = *(const float4*)(fp + d * FS);
                *(float4*)&f[d][4] = *(const float4*)(fp + d * FS + 4);
            }
            const int jE = chunk * 2 + half;   // j-block index for my k-half
            const short8 bfrag =
                *(const short8*)&vlds[(jE * 32 + (il ^ (jE & 7))) * 4];

            float w[8];
            #pragma unroll
            for (int t = 0; t < 8; ++t) {
                float arg = eis + f[5][t];
                arg += si0 * f[0][t];
                arg += si1 * f[1][t];
                arg += si2 * f[2][t];
                arg += si3 * f[3][t];
                arg += si4 * f[4][t];
                w[t] = EXP2F(arg);
            }
            union { unsigned dw[4]; short8 v; } af;
            #pragma unroll
            for (int tp = 0; tp < 4; ++tp) {
                const unsigned u0 = __float_as_uint(w[2 * tp]) + 0x8000u;
                const unsigned u1 = __float_as_uint(w[2 * tp + 1]) + 0x8000u;
                af.dw[tp] = __builtin_amdgcn_perm(u1, u0, 0x07060302u);
            }
            acc = __builtin_amdgcn_mfma_f32_32x32x16_bf16(af.v, bfrag, acc, 0, 0, 0);
        }
    }

    // ---- epilogue: per-wave LDS transpose, then coalesced atomics ----
    __syncthreads();  // all waves done reading staged LDS (tile aliases it)
    float* mytile = tile + wave * 32 * 33;
    // D layout: col(c) = lane&31, row(i) = (r&3) + 8*(r>>2) + 4*half
    #pragma unroll
    for (int r = 0; r < 16; ++r) {
        const int row = (r & 3) + 8 * (r >> 2) + 4 * half;
        mytile[row * 33 + il] = acc[r];
    }
    #pragma unroll
    for (int cc = 0; cc < 11; ++cc) {
        const int c = 2 * cc + half;
        if (c < NC) {
            const float v = mytile[il * 33 + c];
            atomicAdd(&outb[(size_t)c * NN + ibase + isub * 32 + il], v);
        }
    }
}

extern "C" void kernel_launch(void* const* d_in, const int* in_sizes, int n_in,
                              void* d_out, int out_size, void* d_ws, size_t ws_size,
                              hipStream_t stream) {
    const float* cur = (const float*)d_in[0];  // cur_state  [2,21,96,96]
    const float* img = (const float*)d_in[1];  // input_image [2,3,96,96]
    float* out = (float*)d_out;

    // d_out is poisoned with 0xAA before every timed launch -> zero it.
    hipMemsetAsync(out, 0, (size_t)NB * NC * NN * sizeof(float), stream);

    dim3 grid(NIT, G, NB);  // 144 x 12 x 2 = 3456 blocks
    perm_gauss_mfma<<<grid, BLK, 0, stream>>>(cur, img, out);
}

// Round 5
// 97.772 us; speedup vs baseline: 1.6011x; 1.4724x over previous
//
#include <hip/hip_runtime.h>
#include <hip/hip_bf16.h>
#include <math.h>

// Bilateral Gaussian filter: out[b,c,i] = sum_j exp(-0.5|f_i-f_j|^2) * cur[b,c,j]
// f = [y/8, x/8, r/.5, g/.5, b/.5] (D=5). B=2, C=21, N=9216.
//
// Round 5: BOTH matmuls on MFMA.
//  S^T(32j x 32i) = F_j @ F_i^T via one v_mfma_f32_32x32x16_bf16 with
//  split-bf16 K-packing (spatial exact in bf16; color hi+lo; -0.5|f|^2 terms
//  as split-bf16 against unit slots)  ->  fp32-class arg precision.
//  Then per-lane: w = exp2(arg*log2e), packed to bf16; D's lane layout
//  (col=i) IS the P-matrix A-fragment layout (regs 0..7 / 8..15 = the two
//  K=16 A-frags) when V is staged with bits2<->3 of the within-32 j index
//  swapped. acc(32i x 32c) in fp32 AGPRs; epilogue LDS transpose + atomics.
// Prep kernel pre-packs V (bf16, B-frag layout) and F_j A-frags into d_ws.

#define HH 96
#define WW 96
#define NN (HH * WW)   // 9216
#define NB 2
#define NC 21

typedef __attribute__((ext_vector_type(8))) short short8;
typedef __attribute__((ext_vector_type(16))) float f32x16;

constexpr float INV_TA = 0.125f;  // 1/theta_alpha
constexpr float INV_TB = 2.0f;    // 1/theta_beta
constexpr float LOG2E  = 1.44269504088896340736f;

constexpr int BLK    = 256;          // 4 waves
constexpr int ITILE  = 64;           // i per block (2 subtiles of 32)
constexpr int NIT    = NN / ITILE;   // 144
constexpr int G      = 12;           // j-groups
constexpr int JG     = NN / G;       // 768
constexpr int JS     = 256;          // j per staged piece
constexpr int NP     = JG / JS;      // 3
constexpr int NPIECE = NN / JS;      // 36 global pieces
constexpr int NJB    = JS / 32;      // 8 j-blocks per piece

// ws layout: vG [b][piece][unit0..1023][16B]  then  fjaG [b][piece][h][jl][16B]
constexpr size_t VG_BYTES  = (size_t)NB * NPIECE * 1024 * 16;  // 1,179,648
constexpr size_t FJA_OFF   = VG_BYTES;
// LDS: V 16 KB + fjA 8 KB (epilogue tile aliases)
constexpr int VLDS_BYTES   = 1024 * 16;
constexpr int FJA_LDS_OFF  = VLDS_BYTES;
constexpr int SMEM_BYTES   = VLDS_BYTES + 2 * 256 * 16;  // 24576

constexpr int NVU  = NB * NPIECE * 1024;  // 73728 V-pack tasks
constexpr int NFT  = NB * NN;             // 18432 feature tasks
constexpr int PREP_TASKS = NVU + NFT;     // 92160 = 360*256

#if defined(__has_builtin)
#if __has_builtin(__builtin_amdgcn_exp2f)
#define EXP2F(x) __builtin_amdgcn_exp2f(x)
#endif
#endif
#ifndef EXP2F
#define EXP2F(x) exp2f(x)
#endif

__device__ __forceinline__ unsigned short bf16_rne(float f) {
    __hip_bfloat16 h = __float2bfloat16(f);
    unsigned short u; __builtin_memcpy(&u, &h, 2); return u;
}
__device__ __forceinline__ float bf16_f(unsigned short u) {
    __hip_bfloat16 h; __builtin_memcpy(&h, &u, 2); return __bfloat162float(h);
}
// pack two fp32 -> dword of two bf16 (round-up-bias trick; inputs finite)
__device__ __forceinline__ unsigned pk2(float a, float b) {
    const unsigned u0 = __float_as_uint(a) + 0x8000u;
    const unsigned u1 = __float_as_uint(b) + 0x8000u;
    return __builtin_amdgcn_perm(u1, u0, 0x07060302u);  // low=a, high=b
}

// ---------------- prep: pack V and F_j fragments into ws ----------------
__global__ __launch_bounds__(BLK)
void prep_kernel(const float* __restrict__ cur, const float* __restrict__ img,
                 unsigned char* __restrict__ ws) {
    const int t = blockIdx.x * BLK + threadIdx.x;
    if (t < NVU) {
        // V unit: [b][piece][jbl(3)][m(1)][h(1)][c(5)] -> 8 bf16 = V[j(k)][c]
        const int b  = t / (NPIECE * 1024);
        const int r  = t % (NPIECE * 1024);
        const int rr = r & 1023;
        const int piece = r >> 10;
        const int jbl = rr >> 7;
        const int m   = (rr >> 6) & 1;
        const int h   = (rr >> 5) & 1;
        const int c   = rr & 31;
        // k-slot s=8h+t' -> physical j offset = swap bits2,3 of s:
        //   t'=0..3 -> jb+4h+t', t'=4..7 -> jb+8+4h+(t'&3)
        const int jb = piece * 256 + jbl * 32 + m * 16 + 4 * h;
        float4 qa = {0, 0, 0, 0}, qb = {0, 0, 0, 0};
        if (c < NC) {
            const float* row = cur + ((size_t)b * NC + c) * NN;
            qa = *(const float4*)(row + jb);
            qb = *(const float4*)(row + jb + 8);
        }
        uint4 o;
        o.x = pk2(qa.x, qa.y); o.y = pk2(qa.z, qa.w);
        o.z = pk2(qb.x, qb.y); o.w = pk2(qb.z, qb.w);
        *(uint4*)(ws + (size_t)t * 16) = o;
    } else {
        const int tf = t - NVU;
        const int b = tf / NN;
        const int j = tf % NN;
        const float y = (float)(j / WW) * INV_TA;   // exact in bf16
        const float x = (float)(j % WW) * INV_TA;   // exact in bf16
        const float* ib = img + (size_t)b * 3 * NN;
        unsigned short ch[3], cl[3]; float cf[3];
        #pragma unroll
        for (int d = 0; d < 3; ++d) {
            const float c = ib[d * NN + j] * INV_TB;
            ch[d] = bf16_rne(c);
            const float chf = bf16_f(ch[d]);
            cl[d] = bf16_rne(c - chf);
            cf[d] = chf + bf16_f(cl[d]);
        }
        const float e = -0.5f * (y * y + x * x +
                                 cf[0] * cf[0] + cf[1] * cf[1] + cf[2] * cf[2]);
        const unsigned short eh = bf16_rne(e);
        const unsigned short el = bf16_rne(e - bf16_f(eh));
        const unsigned short yb = bf16_rne(y), xb = bf16_rne(x);
        const unsigned short one = 0x3F80;
        const int piece = j >> 8, jl = j & 255;
        unsigned short* u0 = (unsigned short*)
            (ws + FJA_OFF + ((((size_t)b * NPIECE + piece) * 2 + 0) * 256 + jl) * 16);
        unsigned short* u1 = (unsigned short*)
            (ws + FJA_OFF + ((((size_t)b * NPIECE + piece) * 2 + 1) * 256 + jl) * 16);
        // A-frag slots 0-7:  [y, x, ch0,ch1,ch2, cl0,cl1,cl2]
        u0[0] = yb; u0[1] = xb; u0[2] = ch[0]; u0[3] = ch[1]; u0[4] = ch[2];
        u0[5] = cl[0]; u0[6] = cl[1]; u0[7] = cl[2];
        // A-frag slots 8-15: [ch0,ch1,ch2, ejh, ejl, 1, 1, 0]
        u1[0] = ch[0]; u1[1] = ch[1]; u1[2] = ch[2]; u1[3] = eh; u1[4] = el;
        u1[5] = one; u1[6] = one; u1[7] = 0;
    }
}

// ---------------- main kernel ----------------
__global__ __launch_bounds__(BLK)
void perm_gauss_mfma(const float* __restrict__ img,
                     const unsigned char* __restrict__ ws,
                     float* __restrict__ out) {
    __shared__ __align__(16) unsigned char smem[SMEM_BYTES];
    const int tid  = threadIdx.x;
    const int lane = tid & 63;
    const int wave = tid >> 6;
    const int isub = wave & 1;    // i-subtile (32 i's)
    const int jh   = wave >> 1;   // which 4 j-blocks of the piece
    const int il   = lane & 31;
    const int half = lane >> 5;

    const int it = blockIdx.x, g = blockIdx.y, b = blockIdx.z;
    const int ibase = it * ITILE;
    const float* imgb = img + (size_t)b * 3 * NN;
    float* outb = out + (size_t)b * NC * NN;

    // ---- B-operand fragment: F_i for my column i, my k-half ----
    const int ig = ibase + isub * 32 + il;
    const float y = (float)(ig / WW) * INV_TA;
    const float x = (float)(ig % WW) * INV_TA;
    unsigned short ch[3], cl[3]; float cf[3];
    #pragma unroll
    for (int d = 0; d < 3; ++d) {
        const float c = imgb[d * NN + ig] * INV_TB;
        ch[d] = bf16_rne(c);
        const float chf = bf16_f(ch[d]);
        cl[d] = bf16_rne(c - chf);
        cf[d] = chf + bf16_f(cl[d]);
    }
    const float e = -0.5f * (y * y + x * x +
                             cf[0] * cf[0] + cf[1] * cf[1] + cf[2] * cf[2]);
    const unsigned short eh = bf16_rne(e);
    const unsigned short el = bf16_rne(e - bf16_f(eh));
    const unsigned short one = 0x3F80;
    union { unsigned short u[8]; short8 v; } bfi;
    if (half == 0) {
        // B slots 0-7: [y, x, ch0,ch1,ch2, ch0,ch1,ch2]
        bfi.u[0] = bf16_rne(y); bfi.u[1] = bf16_rne(x);
        bfi.u[2] = ch[0]; bfi.u[3] = ch[1]; bfi.u[4] = ch[2];
        bfi.u[5] = ch[0]; bfi.u[6] = ch[1]; bfi.u[7] = ch[2];
    } else {
        // B slots 8-15: [cl0,cl1,cl2, 1, 1, eih, eil, 0]
        bfi.u[0] = cl[0]; bfi.u[1] = cl[1]; bfi.u[2] = cl[2];
        bfi.u[3] = one; bfi.u[4] = one; bfi.u[5] = eh; bfi.u[6] = el;
        bfi.u[7] = 0;
    }

    f32x16 acc, zz;
    #pragma unroll
    for (int r = 0; r < 16; ++r) { acc[r] = 0.0f; zz[r] = 0.0f; }

    for (int p = 0; p < NP; ++p) {
        const int pidx = g * NP + p;   // global piece; j-range pidx*256..+255
        __syncthreads();
        // ---- stage piece: 6 float4 copies/thread (coalesced, conflict-free)
        const float4* vsrc = (const float4*)(ws + ((size_t)b * NPIECE + pidx) * 16384);
        float4* vdst = (float4*)smem;
        #pragma unroll
        for (int k = 0; k < 4; ++k) vdst[k * 256 + tid] = vsrc[k * 256 + tid];
        const float4* fsrc = (const float4*)
            (ws + FJA_OFF + ((size_t)b * NPIECE + pidx) * 8192);
        float4* fdst = (float4*)(smem + FJA_LDS_OFF);
        #pragma unroll
        for (int k = 0; k < 2; ++k) fdst[k * 256 + tid] = fsrc[k * 256 + tid];
        __syncthreads();

        #pragma unroll
        for (int q = 0; q < 4; ++q) {
            const int jbl = jh * 4 + q;
            // S^T = F_j @ F_i^T : A-frag = F_j (rows j), B-frag = F_i (cols i)
            const short8 afj = *(const short8*)
                (smem + FJA_LDS_OFF + (size_t)(half * 256 + jbl * 32 + il) * 16);
            const f32x16 s =
                __builtin_amdgcn_mfma_f32_32x32x16_bf16(afj, bfi.v, zz, 0, 0, 0);
            // w = exp2(arg * log2e); lane's col = i = il -> already P's A-layout
            float w[16];
            #pragma unroll
            for (int r = 0; r < 16; ++r) w[r] = EXP2F(s[r] * LOG2E);
            union { unsigned dw[4]; short8 v; } a1, a2;
            #pragma unroll
            for (int d = 0; d < 4; ++d) {
                a1.dw[d] = pk2(w[2 * d],     w[2 * d + 1]);
                a2.dw[d] = pk2(w[8 + 2 * d], w[9 + 2 * d]);
            }
            const short8 v1 = *(const short8*)
                (smem + (size_t)((4 * jbl + half) * 32 + il) * 16);
            const short8 v2 = *(const short8*)
                (smem + (size_t)((4 * jbl + 2 + half) * 32 + il) * 16);
            acc = __builtin_amdgcn_mfma_f32_32x32x16_bf16(a1.v, v1, acc, 0, 0, 0);
            acc = __builtin_amdgcn_mfma_f32_32x32x16_bf16(a2.v, v2, acc, 0, 0, 0);
        }
    }

    // ---- epilogue: per-wave LDS transpose, then coalesced atomics ----
    __syncthreads();  // all waves done with staged LDS (tile aliases it)
    float* mytile = (float*)smem + wave * 32 * 33;
    #pragma unroll
    for (int r = 0; r < 16; ++r) {
        const int row = (r & 3) + 8 * (r >> 2) + 4 * half;  // i within subtile
        mytile[row * 33 + il] = acc[r];
    }
    #pragma unroll
    for (int cc = 0; cc < 11; ++cc) {
        const int c = 2 * cc + half;
        if (c < NC) {
            const float v = mytile[il * 33 + c];
            atomicAdd(&outb[(size_t)c * NN + ibase + isub * 32 + il], v);
        }
    }
}

extern "C" void kernel_launch(void* const* d_in, const int* in_sizes, int n_in,
                              void* d_out, int out_size, void* d_ws, size_t ws_size,
                              hipStream_t stream) {
    const float* cur = (const float*)d_in[0];  // cur_state  [2,21,96,96]
    const float* img = (const float*)d_in[1];  // input_image [2,3,96,96]
    float* out = (float*)d_out;
    unsigned char* ws = (unsigned char*)d_ws;  // needs ~1.77 MB

    hipMemsetAsync(out, 0, (size_t)NB * NC * NN * sizeof(float), stream);
    prep_kernel<<<PREP_TASKS / BLK, BLK, 0, stream>>>(cur, img, ws);
    dim3 grid(NIT, G, NB);  // 144 x 12 x 2 = 3456 blocks
    perm_gauss_mfma<<<grid, BLK, 0, stream>>>(img, ws, out);
}